// Round 8
// baseline (5052.111 us; speedup 1.0000x reference)
//
#include <hip/hip_runtime.h>
#include <hip/hip_bf16.h>

#define BB 2
#define TT 12
#define NN 20000
#define FF 9
#define HH 64
#define EE 200000

typedef __hip_bfloat16 bf;

// ---- hot buffers in regular (cached) VRAM: static device globals ---------
__device__ unsigned g_xa[NN*HH];      // 5.12 MB  conv1 out (bf16 pair-packed)
__device__ unsigned g_xb[NN*HH];      // 5.12 MB  conv2 out
__device__ float    g_h[NN*BB*FF];    // 1.44 MB  GRU hidden
__device__ int      g_rp[NN+1];
__device__ int      g_cnt[NN];
__device__ int      g_csrc[EE];       // 0.8 MB
__device__ float    g_cw[EE];         // 0.8 MB
__device__ float    g_cvec[32];

__device__ __forceinline__ float lo2f(unsigned u){ unsigned v=u<<16; float f; __builtin_memcpy(&f,&v,4); return f; }
__device__ __forceinline__ float hi2f(unsigned u){ unsigned v=u&0xffff0000u; float f; __builtin_memcpy(&f,&v,4); return f; }
__device__ __forceinline__ unsigned short f2us(float f){ bf h=__float2bfloat16(f); unsigned short u; __builtin_memcpy(&u,&h,2); return u; }
__device__ __forceinline__ unsigned pack2(float a0, float a1){ return (unsigned)f2us(a0) | ((unsigned)f2us(a1)<<16); }
__device__ __forceinline__ float elu(float x){ return x>0.f ? x : expm1f(x); }

// ---- CSR build -----------------------------------------------------------
__global__ void k_zero(){
  int i = blockIdx.x*256 + threadIdx.x;
  if(i < NN) g_cnt[i] = 0;
}

__global__ void k_count(const int* __restrict__ dst){
  int e = blockIdx.x*256 + threadIdx.x;
  if(e < EE) atomicAdd(&g_cnt[dst[e]], 1);
}

__global__ void k_scan(){
  __shared__ int part[256];
  const int CH = 79;                       // 256*79 = 20224 >= 20000
  int t = threadIdx.x;
  int base = t*CH;
  int s = 0;
  for(int i=0;i<CH;i++){ int idx=base+i; if(idx<NN) s += g_cnt[idx]; }
  part[t] = s; __syncthreads();
  for(int off=1; off<256; off<<=1){
    int v = (t>=off) ? part[t-off] : 0;
    __syncthreads();
    part[t] += v;
    __syncthreads();
  }
  int run = (t==0) ? 0 : part[t-1];
  for(int i=0;i<CH;i++){
    int idx=base+i;
    if(idx<NN){ run += g_cnt[idx]; g_rp[idx+1] = run; }
  }
  if(t==0) g_rp[0] = 0;
}

__global__ void k_fill(const int* __restrict__ dst, const int* __restrict__ src,
                       const float* __restrict__ ew){
  int e = blockIdx.x*256 + threadIdx.x;
  if(e >= EE) return;
  int d = dst[e];
  int pos = g_rp[d] + atomicAdd(&g_cnt[d], 1);
  g_csrc[pos] = src[e];
  g_cw[pos]   = ew[e];
}

// ---- head precompute -----------------------------------------------------
__global__ void k_head(const float* __restrict__ encW, const float* __restrict__ encb,
                       const float* __restrict__ decW, const float* __restrict__ decb,
                       const float* __restrict__ te){
  __shared__ float c[19];
  int tid = threadIdx.x;
  if(tid < 18){ float s=0.f; for(int j=0;j<64;j++) s += encW[tid*64+j]*decW[j]; c[tid]=s; }
  if(tid == 18){ float s=decb[0]; for(int j=0;j<64;j++) s += encb[j]*decW[j]; c[18]=s; }
  __syncthreads();
  if(tid < FF) g_cvec[tid] = c[tid];
  if(tid < BB){ float s=c[18]; for(int k=0;k<FF;k++) s += te[tid*FF+k]*c[9+k]; g_cvec[FF+tid]=s; }
}

// ---- conv1: 9 -> 64 ------------------------------------------------------
__global__ void k_conv1(const float* __restrict__ g, int t,
                        const float* __restrict__ Wl, const float* __restrict__ bias,
                        const float* __restrict__ Wr){
  __shared__ float sWl[FF*HH], sWr[FF*HH], sb[HH];
  int tid = threadIdx.x;
  for(int i=tid;i<FF*HH;i+=256){ sWl[i]=Wl[t*FF*HH+i]; sWr[i]=Wr[t*FF*HH+i]; }
  if(tid<HH) sb[tid]=bias[t*HH+tid];
  __syncthreads();
  int lane = tid & 63;
  int half = lane>>5, l9 = lane&31;        // half = batch; lanes {0..8, 32..40} gather
  bool act = l9 < FF;
  int wid = (blockIdx.x*256+tid)>>6, nw = gridDim.x*4;
  long gb = ((long)(half*TT+t)*NN)*FF;
  for(int n=wid; n<NN; n+=nw){
    int r0=g_rp[n], r1=g_rp[n+1];
    float dg = fmaxf((float)(r1-r0), 1.f);
    float xv=0.f, agg=0.f;
    if(act) xv = g[gb + (long)n*FF + l9];
    for(int base=r0; base<r1; base+=64){
      int cnt = min(64, r1-base);
      int ms = 0; float mw = 0.f;
      if(lane < cnt){ ms = g_csrc[base+lane]; mw = g_cw[base+lane]; }
      for(int k=0;k<cnt;k+=4){
        int   s0=__shfl(ms,k,64),   s1=__shfl(ms,k+1,64),   s2=__shfl(ms,k+2,64),   s3=__shfl(ms,k+3,64);
        float w0=__shfl(mw,k,64),   w1=__shfl(mw,k+1,64),   w2=__shfl(mw,k+2,64),   w3=__shfl(mw,k+3,64);
        if(act){
          float v0=g[gb+(long)s0*FF+l9], v1=g[gb+(long)s1*FF+l9];
          float v2=g[gb+(long)s2*FF+l9], v3=g[gb+(long)s3*FF+l9];
          agg += w0*v0 + w1*v1 + w2*v2 + w3*v3;
        }
      }
    }
    agg /= dg;
    float a0 = sb[lane], a1 = sb[lane];
    #pragma unroll
    for(int f=0; f<FF; f++){
      float av0=__shfl(agg,f,64),    sv0=__shfl(xv,f,64);
      float av1=__shfl(agg,32+f,64), sv1=__shfl(xv,32+f,64);
      float wl=sWl[f*HH+lane], wr=sWr[f*HH+lane];
      a0 += av0*wl + sv0*wr;
      a1 += av1*wl + sv1*wr;
    }
    g_xa[n*HH+lane] = pack2(elu(a0), elu(a1));
  }
}

// ---- conv2: 64 -> 64, dwordx4 gather: 4 edges/wave-instr, 16 lanes/row --
__global__ void k_conv2(int t,
                        const float* __restrict__ Wl, const float* __restrict__ bias,
                        const float* __restrict__ Wr){
  __shared__ float sWl[HH*HH], sWr[HH*HH], sb[HH];
  int tid = threadIdx.x;
  for(int i=tid;i<HH*HH;i+=256){ sWl[i]=Wl[t*HH*HH+i]; sWr[i]=Wr[t*HH*HH+i]; }
  if(tid<HH) sb[tid]=bias[t*HH+tid];
  __syncthreads();
  int lane = tid & 63;
  int grp  = lane >> 4;                    // edge group 0..3
  int sub  = lane & 15;                    // 16-B chunk within row
  int wid = (blockIdx.x*256+tid)>>6, nw = gridDim.x*4;
  for(int n=wid; n<NN; n+=nw){
    int r0=g_rp[n], r1=g_rp[n+1];
    float dg = fmaxf((float)(r1-r0), 1.f);
    unsigned su = g_xa[n*HH+lane];
    float xv0 = lo2f(su), xv1 = hi2f(su);
    float p0[4]={0.f,0.f,0.f,0.f}, p1[4]={0.f,0.f,0.f,0.f};
    for(int base=r0; base<r1; base+=64){
      int cnt = min(64, r1-base);
      int ms = 0; float mw = 0.f;
      if(lane < cnt){ ms = g_csrc[base+lane]; mw = g_cw[base+lane]; }
      for(int k=0;k<cnt;k+=4){
        int   sg = __shfl(ms, k+grp, 64);  // per-lane src (OOB lanes: s=0,w=0)
        float wg = __shfl(mw, k+grp, 64);
        const uint4 v = *reinterpret_cast<const uint4*>(g_xa + (size_t)sg*HH + (sub<<2));
        p0[0]+=wg*lo2f(v.x); p1[0]+=wg*hi2f(v.x);
        p0[1]+=wg*lo2f(v.y); p1[1]+=wg*hi2f(v.y);
        p0[2]+=wg*lo2f(v.z); p1[2]+=wg*hi2f(v.z);
        p0[3]+=wg*lo2f(v.w); p1[3]+=wg*hi2f(v.w);
      }
    }
    #pragma unroll
    for(int q=0;q<4;q++){
      p0[q] += __shfl_xor(p0[q],16,64); p1[q] += __shfl_xor(p1[q],16,64);
      p0[q] += __shfl_xor(p0[q],32,64); p1[q] += __shfl_xor(p1[q],32,64);
      p0[q] /= dg; p1[q] /= dg;
    }
    // lanes 0..15 hold agg features 4*lane+q
    float a0 = sb[lane], a1 = sb[lane];
    #pragma unroll
    for(int i=0;i<HH;i++){
      float av0=__shfl(p0[i&3], i>>2, 64);
      float av1=__shfl(p1[i&3], i>>2, 64);
      float sv0=__shfl(xv0, i, 64);
      float sv1=__shfl(xv1, i, 64);
      float wl=sWl[i*HH+lane], wr=sWr[i*HH+lane];
      a0 += av0*wl + sv0*wr;
      a1 += av1*wl + sv1*wr;
    }
    g_xb[n*HH+lane] = pack2(elu(a0), elu(a1));
  }
}

// ---- conv3 (64->9) + GRU(9->9) + head + mask, dwordx4 gather ------------
__global__ void k_conv3g(int t,
                         const float* __restrict__ Wl, const float* __restrict__ bias,
                         const float* __restrict__ Wr,
                         const float* __restrict__ Wih, const float* __restrict__ Whh,
                         const float* __restrict__ bih, const float* __restrict__ bhh,
                         const float* __restrict__ g, float* __restrict__ out){
  __shared__ float sWl[HH*FF], sWr[HH*FF], sb[FF];
  __shared__ float sWi[FF*27], sWh[FF*27], sbi[27], sbh[27], sc[FF+BB];
  int tid = threadIdx.x;
  for(int i=tid;i<HH*FF;i+=256){ sWl[i]=Wl[t*HH*FF+i]; sWr[i]=Wr[t*HH*FF+i]; }
  for(int i=tid;i<FF*27;i+=256){ sWi[i]=Wih[t*FF*27+i]; sWh[i]=Whh[t*FF*27+i]; }
  if(tid<27){ sbi[tid]=bih[t*27+tid]; sbh[tid]=bhh[t*27+tid]; }
  if(tid<FF) sb[tid]=bias[t*FF+tid];
  if(tid<FF+BB) sc[tid]=g_cvec[tid];
  __syncthreads();
  int lane = tid & 63;
  int grp  = lane >> 4;
  int sub  = lane & 15;
  int wid = (blockIdx.x*256+tid)>>6, nw = gridDim.x*4;
  for(int n=wid; n<NN; n+=nw){
    int r0=g_rp[n], r1=g_rp[n+1];
    float dg = fmaxf((float)(r1-r0), 1.f);
    unsigned su = g_xb[n*HH+lane];
    float xv0 = lo2f(su), xv1 = hi2f(su);
    float p0[4]={0.f,0.f,0.f,0.f}, p1[4]={0.f,0.f,0.f,0.f};
    for(int base=r0; base<r1; base+=64){
      int cnt = min(64, r1-base);
      int ms = 0; float mw = 0.f;
      if(lane < cnt){ ms = g_csrc[base+lane]; mw = g_cw[base+lane]; }
      for(int k=0;k<cnt;k+=4){
        int   sg = __shfl(ms, k+grp, 64);
        float wg = __shfl(mw, k+grp, 64);
        const uint4 v = *reinterpret_cast<const uint4*>(g_xb + (size_t)sg*HH + (sub<<2));
        p0[0]+=wg*lo2f(v.x); p1[0]+=wg*hi2f(v.x);
        p0[1]+=wg*lo2f(v.y); p1[1]+=wg*hi2f(v.y);
        p0[2]+=wg*lo2f(v.z); p1[2]+=wg*hi2f(v.z);
        p0[3]+=wg*lo2f(v.w); p1[3]+=wg*hi2f(v.w);
      }
    }
    #pragma unroll
    for(int q=0;q<4;q++){
      p0[q] += __shfl_xor(p0[q],16,64); p1[q] += __shfl_xor(p1[q],16,64);
      p0[q] += __shfl_xor(p0[q],32,64); p1[q] += __shfl_xor(p1[q],32,64);
      p0[q] /= dg; p1[q] /= dg;
    }
    // dense 64->9: lane<16 contributes its 4 agg features; all lanes their xv
    float part0[FF], part1[FF];
    bool own = (lane < 16);
    #pragma unroll
    for(int f=0;f<FF;f++){
      float s0 = xv0*sWr[lane*FF+f];
      float s1 = xv1*sWr[lane*FF+f];
      if(own){
        #pragma unroll
        for(int q=0;q<4;q++){
          int i = (lane<<2)+q;
          s0 += p0[q]*sWl[i*FF+f];
          s1 += p1[q]*sWl[i*FF+f];
        }
      }
      part0[f]=s0; part1[f]=s1;
    }
    #pragma unroll
    for(int f=0;f<FF;f++){
      #pragma unroll
      for(int m=32;m>=1;m>>=1){ part0[f] += __shfl_xor(part0[f], m, 64); part1[f] += __shfl_xor(part1[f], m, 64); }
    }
    float x0[FF], x1[FF];
    #pragma unroll
    for(int f=0;f<FF;f++){ x0[f] = elu(part0[f]+sb[f]); x1[f] = elu(part1[f]+sb[f]); }

    if(lane < 18){
      int b = (lane >= FF) ? 1 : 0;
      int f = lane - FF*b;
      long hidx = (long)(n*BB + b)*FF + f;
      float hp_own = (t==0) ? 0.f : g_h[hidx];
      float hp[FF];
      #pragma unroll
      for(int i=0;i<FF;i++) hp[i] = __shfl(hp_own, b*FF+i, 64);
      float gir=sbi[f], giz=sbi[9+f], gin=sbi[18+f];
      float ghr=sbh[f], ghz=sbh[9+f], ghn=sbh[18+f];
      #pragma unroll
      for(int i=0;i<FF;i++){
        float xi = b ? x1[i] : x0[i];
        gir += xi*sWi[i*27+f];  giz += xi*sWi[i*27+9+f];  gin += xi*sWi[i*27+18+f];
        ghr += hp[i]*sWh[i*27+f]; ghz += hp[i]*sWh[i*27+9+f]; ghn += hp[i]*sWh[i*27+18+f];
      }
      float r = 1.f/(1.f+__expf(-(gir+ghr)));
      float z = 1.f/(1.f+__expf(-(giz+ghz)));
      float nv = tanhf(gin + r*ghn);
      float hv = (1.f-z)*nv + z*hp_own;
      g_h[hidx] = hv;
      float v = hv*sc[f];
      float hs = v;
      #pragma unroll
      for(int j=1;j<FF;j++) hs += __shfl(v, b*FF+j, 64);
      if(f==0){
        long gi = (long)(b*TT+t)*NN + n;
        float m = (g[gi*FF] != 0.f) ? 1.f : 0.f;
        out[gi] = (hs + sc[FF+b])*m;
      }
    }
  }
}

extern "C" void kernel_launch(void* const* d_in, const int* in_sizes, int n_in,
                              void* d_out, int out_size, void* d_ws, size_t ws_size,
                              hipStream_t stream){
  const float* g    = (const float*)d_in[0];
  const float* te   = (const float*)d_in[1];
  const float* ew   = (const float*)d_in[3];
  const int* esrc = (const int*)d_in[4];
  const int* edst = (const int*)d_in[5];
  const float* W1l=(const float*)d_in[6];  const float* b1 =(const float*)d_in[7];  const float* W1r=(const float*)d_in[8];
  const float* W2l=(const float*)d_in[9];  const float* b2 =(const float*)d_in[10]; const float* W2r=(const float*)d_in[11];
  const float* W3l=(const float*)d_in[12]; const float* b3 =(const float*)d_in[13]; const float* W3r=(const float*)d_in[14];
  const float* Wih=(const float*)d_in[15]; const float* Whh=(const float*)d_in[16];
  const float* bih=(const float*)d_in[17]; const float* bhh=(const float*)d_in[18];
  const float* encW=(const float*)d_in[19]; const float* encb=(const float*)d_in[20];
  const float* decW=(const float*)d_in[21]; const float* decb=(const float*)d_in[22];
  float* out = (float*)d_out;

  k_zero <<<(NN+255)/256, 256, 0, stream>>>();
  k_count<<<(EE+255)/256, 256, 0, stream>>>(edst);
  k_scan <<<1, 256, 0, stream>>>();
  k_zero <<<(NN+255)/256, 256, 0, stream>>>();
  k_fill <<<(EE+255)/256, 256, 0, stream>>>(edst, esrc, ew);
  k_head <<<1, 64, 0, stream>>>(encW, encb, decW, decb, te);

  const int CB = 1024;   // 4 waves/block; conv2 LDS 33KB -> 4 blocks/CU
  for(int t=0; t<TT; t++){
    k_conv1 <<<CB, 256, 0, stream>>>(g, t, W1l, b1, W1r);
    k_conv2 <<<CB, 256, 0, stream>>>(t, W2l, b2, W2r);
    k_conv3g<<<CB, 256, 0, stream>>>(t, W3l, b3, W3r, Wih, Whh, bih, bhh, g, out);
  }
}

// Round 9
// 1433.765 us; speedup vs baseline: 3.5237x; 3.5237x over previous
//
#include <hip/hip_runtime.h>
#include <hip/hip_bf16.h>

#define BB 2
#define TT 12
#define NN 20000
#define FF 9
#define HH 64
#define EE 200000

typedef __hip_bfloat16 bf;
typedef __attribute__((ext_vector_type(8))) short s8v;   // 8 bf16 (4 VGPRs)
typedef __attribute__((ext_vector_type(4))) float f4v;

// ---- hot buffers: static device globals ----------------------------------
__device__ unsigned g_xa[NN*HH];      // conv1 out (bf16 pair-packed)
__device__ unsigned g_ag[NN*HH];      // conv2 aggregation (bf16 pair-packed, /deg applied)
__device__ unsigned g_xb[NN*HH];      // conv2 out
__device__ float    g_h[NN*BB*FF];    // GRU hidden
__device__ int      g_rp[NN+1];
__device__ int      g_cnt[NN];
__device__ int      g_csrc[EE];
__device__ float    g_cw[EE];
__device__ float    g_cvec[32];

__device__ __forceinline__ float lo2f(unsigned u){ unsigned v=u<<16; float f; __builtin_memcpy(&f,&v,4); return f; }
__device__ __forceinline__ float hi2f(unsigned u){ unsigned v=u&0xffff0000u; float f; __builtin_memcpy(&f,&v,4); return f; }
__device__ __forceinline__ unsigned short f2us(float f){ bf h=__float2bfloat16(f); unsigned short u; __builtin_memcpy(&u,&h,2); return u; }
__device__ __forceinline__ unsigned pack2(float a0, float a1){ return (unsigned)f2us(a0) | ((unsigned)f2us(a1)<<16); }
__device__ __forceinline__ float elu(float x){ return x>0.f ? x : expm1f(x); }

// ---- CSR build -----------------------------------------------------------
__global__ void k_zero(){
  int i = blockIdx.x*256 + threadIdx.x;
  if(i < NN) g_cnt[i] = 0;
}

__global__ void k_count(const int* __restrict__ dst){
  int e = blockIdx.x*256 + threadIdx.x;
  if(e < EE) atomicAdd(&g_cnt[dst[e]], 1);
}

__global__ void k_scan(){
  __shared__ int part[256];
  const int CH = 79;
  int t = threadIdx.x;
  int base = t*CH;
  int s = 0;
  for(int i=0;i<CH;i++){ int idx=base+i; if(idx<NN) s += g_cnt[idx]; }
  part[t] = s; __syncthreads();
  for(int off=1; off<256; off<<=1){
    int v = (t>=off) ? part[t-off] : 0;
    __syncthreads();
    part[t] += v;
    __syncthreads();
  }
  int run = (t==0) ? 0 : part[t-1];
  for(int i=0;i<CH;i++){
    int idx=base+i;
    if(idx<NN){ run += g_cnt[idx]; g_rp[idx+1] = run; }
  }
  if(t==0) g_rp[0] = 0;
}

__global__ void k_fill(const int* __restrict__ dst, const int* __restrict__ src,
                       const float* __restrict__ ew){
  int e = blockIdx.x*256 + threadIdx.x;
  if(e >= EE) return;
  int d = dst[e];
  int pos = g_rp[d] + atomicAdd(&g_cnt[d], 1);
  g_csrc[pos] = src[e];
  g_cw[pos]   = ew[e];
}

// ---- head precompute -----------------------------------------------------
__global__ void k_head(const float* __restrict__ encW, const float* __restrict__ encb,
                       const float* __restrict__ decW, const float* __restrict__ decb,
                       const float* __restrict__ te){
  __shared__ float c[19];
  int tid = threadIdx.x;
  if(tid < 18){ float s=0.f; for(int j=0;j<64;j++) s += encW[tid*64+j]*decW[j]; c[tid]=s; }
  if(tid == 18){ float s=decb[0]; for(int j=0;j<64;j++) s += encb[j]*decW[j]; c[18]=s; }
  __syncthreads();
  if(tid < FF) g_cvec[tid] = c[tid];
  if(tid < BB){ float s=c[18]; for(int k=0;k<FF;k++) s += te[tid*FF+k]*c[9+k]; g_cvec[FF+tid]=s; }
}

// ---- conv1: 9 -> 64 (K=9 shuffle form is cheap; unchanged) ---------------
__global__ void k_conv1(const float* __restrict__ g, int t,
                        const float* __restrict__ Wl, const float* __restrict__ bias,
                        const float* __restrict__ Wr){
  __shared__ float sWl[FF*HH], sWr[FF*HH], sb[HH];
  int tid = threadIdx.x;
  for(int i=tid;i<FF*HH;i+=256){ sWl[i]=Wl[t*FF*HH+i]; sWr[i]=Wr[t*FF*HH+i]; }
  if(tid<HH) sb[tid]=bias[t*HH+tid];
  __syncthreads();
  int lane = tid & 63;
  int half = lane>>5, l9 = lane&31;
  bool act = l9 < FF;
  int wid = (blockIdx.x*256+tid)>>6, nw = gridDim.x*4;
  long gb = ((long)(half*TT+t)*NN)*FF;
  for(int n=wid; n<NN; n+=nw){
    int r0=g_rp[n], r1=g_rp[n+1];
    float dg = fmaxf((float)(r1-r0), 1.f);
    float xv=0.f, agg=0.f;
    if(act) xv = g[gb + (long)n*FF + l9];
    for(int base=r0; base<r1; base+=64){
      int cnt = min(64, r1-base);
      int ms = 0; float mw = 0.f;
      if(lane < cnt){ ms = g_csrc[base+lane]; mw = g_cw[base+lane]; }
      for(int k=0;k<cnt;k+=4){
        int   s0=__shfl(ms,k,64),   s1=__shfl(ms,k+1,64),   s2=__shfl(ms,k+2,64),   s3=__shfl(ms,k+3,64);
        float w0=__shfl(mw,k,64),   w1=__shfl(mw,k+1,64),   w2=__shfl(mw,k+2,64),   w3=__shfl(mw,k+3,64);
        if(act){
          float v0=g[gb+(long)s0*FF+l9], v1=g[gb+(long)s1*FF+l9];
          float v2=g[gb+(long)s2*FF+l9], v3=g[gb+(long)s3*FF+l9];
          agg += w0*v0 + w1*v1 + w2*v2 + w3*v3;
        }
      }
    }
    agg /= dg;
    float a0 = sb[lane], a1 = sb[lane];
    #pragma unroll
    for(int f=0; f<FF; f++){
      float av0=__shfl(agg,f,64),    sv0=__shfl(xv,f,64);
      float av1=__shfl(agg,32+f,64), sv1=__shfl(xv,32+f,64);
      float wl=sWl[f*HH+lane], wr=sWr[f*HH+lane];
      a0 += av0*wl + sv0*wr;
      a1 += av1*wl + sv1*wr;
    }
    g_xa[n*HH+lane] = pack2(elu(a0), elu(a1));
  }
}

// ---- k_agg: pure gather+reduce for conv2 aggregation --------------------
__global__ void k_agg(){
  int tid = threadIdx.x;
  int lane = tid & 63;
  int grp  = lane >> 4;
  int sub  = lane & 15;
  int wid = (blockIdx.x*256+tid)>>6, nw = gridDim.x*4;
  for(int n=wid; n<NN; n+=nw){
    int r0=g_rp[n], r1=g_rp[n+1];
    float dg = fmaxf((float)(r1-r0), 1.f);
    float p0[4]={0.f,0.f,0.f,0.f}, p1[4]={0.f,0.f,0.f,0.f};
    for(int base=r0; base<r1; base+=64){
      int cnt = min(64, r1-base);
      int ms = 0; float mw = 0.f;
      if(lane < cnt){ ms = g_csrc[base+lane]; mw = g_cw[base+lane]; }
      for(int k=0;k<cnt;k+=4){
        int   sg = __shfl(ms, k+grp, 64);
        float wg = __shfl(mw, k+grp, 64);
        const uint4 v = *reinterpret_cast<const uint4*>(g_xa + (size_t)sg*HH + (sub<<2));
        p0[0]+=wg*lo2f(v.x); p1[0]+=wg*hi2f(v.x);
        p0[1]+=wg*lo2f(v.y); p1[1]+=wg*hi2f(v.y);
        p0[2]+=wg*lo2f(v.z); p1[2]+=wg*hi2f(v.z);
        p0[3]+=wg*lo2f(v.w); p1[3]+=wg*hi2f(v.w);
      }
    }
    #pragma unroll
    for(int q=0;q<4;q++){
      p0[q] += __shfl_xor(p0[q],16,64); p1[q] += __shfl_xor(p1[q],16,64);
      p0[q] += __shfl_xor(p0[q],32,64); p1[q] += __shfl_xor(p1[q],32,64);
    }
    if(lane < 16){
      uint4 o;
      o.x = pack2(p0[0]/dg, p1[0]/dg);
      o.y = pack2(p0[1]/dg, p1[1]/dg);
      o.z = pack2(p0[2]/dg, p1[2]/dg);
      o.w = pack2(p0[3]/dg, p1[3]/dg);
      *reinterpret_cast<uint4*>(g_ag + (size_t)n*HH + (lane<<2)) = o;
    }
  }
}

// ---- k_gemm: ELU([AGG|X] @ [Wl;Wr] + b) via MFMA 16x16x32 bf16 ----------
// A: m=lane&15, k=quad*8+j  |  B: n=lane&15, k=quad*8+j  |  C/D: col=lane&15, row=quad*4+reg
__global__ __launch_bounds__(256) void k_gemm(int t, const float* __restrict__ Wl,
                                              const float* __restrict__ bias,
                                              const float* __restrict__ Wr){
  int tid = threadIdx.x, lane = tid & 63, wave = tid >> 6;
  int quad = lane >> 4, col = lane & 15;
  int base16 = blockIdx.x*64 + wave*16;
  if(base16 >= NN) return;                 // NN = 16*1250: tiles are exact
  int nodeA = base16 + col;                // A-operand row (m)
  // A fragments: 4 K-steps (0,1 = AGG feats 0-31/32-63; 2,3 = X) x 2 batches
  s8v A0[4], A1[4];
  #pragma unroll
  for(int ks=0; ks<4; ks++){
    const unsigned* srcb = (ks < 2) ? g_ag : g_xa;
    int koff = (ks & 1)*32 + quad*8;
    const uint4 u = *reinterpret_cast<const uint4*>(srcb + (size_t)nodeA*HH + koff);
    const uint4 v = *reinterpret_cast<const uint4*>(srcb + (size_t)nodeA*HH + koff + 4);
    unsigned uu[8] = {u.x,u.y,u.z,u.w,v.x,v.y,v.z,v.w};
    #pragma unroll
    for(int j=0;j<8;j++){
      A0[ks][j] = (short)(uu[j] & 0xffffu);
      A1[ks][j] = (short)(uu[j] >> 16);
    }
  }
  #pragma unroll
  for(int nt=0; nt<4; nt++){
    f4v c0 = {0.f,0.f,0.f,0.f}, c1 = {0.f,0.f,0.f,0.f};
    #pragma unroll
    for(int ks=0; ks<4; ks++){
      s8v B;
      #pragma unroll
      for(int j=0;j<8;j++){
        int k = ks*32 + quad*8 + j;        // 0..127
        float wv = (k < HH) ? Wl[(size_t)t*HH*HH + (size_t)k*HH + nt*16 + col]
                            : Wr[(size_t)t*HH*HH + (size_t)(k-HH)*HH + nt*16 + col];
        B[j] = (short)f2us(wv);
      }
      c0 = __builtin_amdgcn_mfma_f32_16x16x32_bf16(A0[ks], B, c0, 0, 0, 0);
      c1 = __builtin_amdgcn_mfma_f32_16x16x32_bf16(A1[ks], B, c1, 0, 0, 0);
    }
    float bn = bias[t*HH + nt*16 + col];
    #pragma unroll
    for(int reg=0; reg<4; reg++){
      int node = base16 + quad*4 + reg;    // C/D row
      g_xb[(size_t)node*HH + nt*16 + col] = pack2(elu(c0[reg]+bn), elu(c1[reg]+bn));
    }
  }
}

// ---- conv3 (64->9) + GRU(9->9) + head + mask (unchanged) ----------------
__global__ void k_conv3g(int t,
                         const float* __restrict__ Wl, const float* __restrict__ bias,
                         const float* __restrict__ Wr,
                         const float* __restrict__ Wih, const float* __restrict__ Whh,
                         const float* __restrict__ bih, const float* __restrict__ bhh,
                         const float* __restrict__ g, float* __restrict__ out){
  __shared__ float sWl[HH*FF], sWr[HH*FF], sb[FF];
  __shared__ float sWi[FF*27], sWh[FF*27], sbi[27], sbh[27], sc[FF+BB];
  int tid = threadIdx.x;
  for(int i=tid;i<HH*FF;i+=256){ sWl[i]=Wl[t*HH*FF+i]; sWr[i]=Wr[t*HH*FF+i]; }
  for(int i=tid;i<FF*27;i+=256){ sWi[i]=Wih[t*FF*27+i]; sWh[i]=Whh[t*FF*27+i]; }
  if(tid<27){ sbi[tid]=bih[t*27+tid]; sbh[tid]=bhh[t*27+tid]; }
  if(tid<FF) sb[tid]=bias[t*FF+tid];
  if(tid<FF+BB) sc[tid]=g_cvec[tid];
  __syncthreads();
  int lane = tid & 63;
  int grp  = lane >> 4;
  int sub  = lane & 15;
  int wid = (blockIdx.x*256+tid)>>6, nw = gridDim.x*4;
  for(int n=wid; n<NN; n+=nw){
    int r0=g_rp[n], r1=g_rp[n+1];
    float dg = fmaxf((float)(r1-r0), 1.f);
    unsigned su = g_xb[n*HH+lane];
    float xv0 = lo2f(su), xv1 = hi2f(su);
    float p0[4]={0.f,0.f,0.f,0.f}, p1[4]={0.f,0.f,0.f,0.f};
    for(int base=r0; base<r1; base+=64){
      int cnt = min(64, r1-base);
      int ms = 0; float mw = 0.f;
      if(lane < cnt){ ms = g_csrc[base+lane]; mw = g_cw[base+lane]; }
      for(int k=0;k<cnt;k+=4){
        int   sg = __shfl(ms, k+grp, 64);
        float wg = __shfl(mw, k+grp, 64);
        const uint4 v = *reinterpret_cast<const uint4*>(g_xb + (size_t)sg*HH + (sub<<2));
        p0[0]+=wg*lo2f(v.x); p1[0]+=wg*hi2f(v.x);
        p0[1]+=wg*lo2f(v.y); p1[1]+=wg*hi2f(v.y);
        p0[2]+=wg*lo2f(v.z); p1[2]+=wg*hi2f(v.z);
        p0[3]+=wg*lo2f(v.w); p1[3]+=wg*hi2f(v.w);
      }
    }
    #pragma unroll
    for(int q=0;q<4;q++){
      p0[q] += __shfl_xor(p0[q],16,64); p1[q] += __shfl_xor(p1[q],16,64);
      p0[q] += __shfl_xor(p0[q],32,64); p1[q] += __shfl_xor(p1[q],32,64);
      p0[q] /= dg; p1[q] /= dg;
    }
    float part0[FF], part1[FF];
    bool own = (lane < 16);
    #pragma unroll
    for(int f=0;f<FF;f++){
      float s0 = xv0*sWr[lane*FF+f];
      float s1 = xv1*sWr[lane*FF+f];
      if(own){
        #pragma unroll
        for(int q=0;q<4;q++){
          int i = (lane<<2)+q;
          s0 += p0[q]*sWl[i*FF+f];
          s1 += p1[q]*sWl[i*FF+f];
        }
      }
      part0[f]=s0; part1[f]=s1;
    }
    #pragma unroll
    for(int f=0;f<FF;f++){
      #pragma unroll
      for(int m=32;m>=1;m>>=1){ part0[f] += __shfl_xor(part0[f], m, 64); part1[f] += __shfl_xor(part1[f], m, 64); }
    }
    float x0[FF], x1[FF];
    #pragma unroll
    for(int f=0;f<FF;f++){ x0[f] = elu(part0[f]+sb[f]); x1[f] = elu(part1[f]+sb[f]); }

    if(lane < 18){
      int b = (lane >= FF) ? 1 : 0;
      int f = lane - FF*b;
      long hidx = (long)(n*BB + b)*FF + f;
      float hp_own = (t==0) ? 0.f : g_h[hidx];
      float hp[FF];
      #pragma unroll
      for(int i=0;i<FF;i++) hp[i] = __shfl(hp_own, b*FF+i, 64);
      float gir=sbi[f], giz=sbi[9+f], gin=sbi[18+f];
      float ghr=sbh[f], ghz=sbh[9+f], ghn=sbh[18+f];
      #pragma unroll
      for(int i=0;i<FF;i++){
        float xi = b ? x1[i] : x0[i];
        gir += xi*sWi[i*27+f];  giz += xi*sWi[i*27+9+f];  gin += xi*sWi[i*27+18+f];
        ghr += hp[i]*sWh[i*27+f]; ghz += hp[i]*sWh[i*27+9+f]; ghn += hp[i]*sWh[i*27+18+f];
      }
      float r = 1.f/(1.f+__expf(-(gir+ghr)));
      float z = 1.f/(1.f+__expf(-(giz+ghz)));
      float nv = tanhf(gin + r*ghn);
      float hv = (1.f-z)*nv + z*hp_own;
      g_h[hidx] = hv;
      float v = hv*sc[f];
      float hs = v;
      #pragma unroll
      for(int j=1;j<FF;j++) hs += __shfl(v, b*FF+j, 64);
      if(f==0){
        long gi = (long)(b*TT+t)*NN + n;
        float m = (g[gi*FF] != 0.f) ? 1.f : 0.f;
        out[gi] = (hs + sc[FF+b])*m;
      }
    }
  }
}

extern "C" void kernel_launch(void* const* d_in, const int* in_sizes, int n_in,
                              void* d_out, int out_size, void* d_ws, size_t ws_size,
                              hipStream_t stream){
  const float* g    = (const float*)d_in[0];
  const float* te   = (const float*)d_in[1];
  const float* ew   = (const float*)d_in[3];
  const int* esrc = (const int*)d_in[4];
  const int* edst = (const int*)d_in[5];
  const float* W1l=(const float*)d_in[6];  const float* b1 =(const float*)d_in[7];  const float* W1r=(const float*)d_in[8];
  const float* W2l=(const float*)d_in[9];  const float* b2 =(const float*)d_in[10]; const float* W2r=(const float*)d_in[11];
  const float* W3l=(const float*)d_in[12]; const float* b3 =(const float*)d_in[13]; const float* W3r=(const float*)d_in[14];
  const float* Wih=(const float*)d_in[15]; const float* Whh=(const float*)d_in[16];
  const float* bih=(const float*)d_in[17]; const float* bhh=(const float*)d_in[18];
  const float* encW=(const float*)d_in[19]; const float* encb=(const float*)d_in[20];
  const float* decW=(const float*)d_in[21]; const float* decb=(const float*)d_in[22];
  float* out = (float*)d_out;

  k_zero <<<(NN+255)/256, 256, 0, stream>>>();
  k_count<<<(EE+255)/256, 256, 0, stream>>>(edst);
  k_scan <<<1, 256, 0, stream>>>();
  k_zero <<<(NN+255)/256, 256, 0, stream>>>();
  k_fill <<<(EE+255)/256, 256, 0, stream>>>(edst, esrc, ew);
  k_head <<<1, 64, 0, stream>>>(encW, encb, decW, decb, te);

  const int CB = 1024;
  const int GB = (NN + 63)/64;   // 313 blocks, 64 nodes each (16-node wave tiles)
  for(int t=0; t<TT; t++){
    k_conv1 <<<CB, 256, 0, stream>>>(g, t, W1l, b1, W1r);
    k_agg   <<<CB, 256, 0, stream>>>();
    k_gemm  <<<GB, 256, 0, stream>>>(t, W2l, b2, W2r);
    k_conv3g<<<CB, 256, 0, stream>>>(t, W3l, b3, W3r, Wih, Whh, bih, bhh, g, out);
  }
}

// Round 10
// 1120.619 us; speedup vs baseline: 4.5083x; 1.2794x over previous
//
#include <hip/hip_runtime.h>
#include <hip/hip_bf16.h>

#define BB 2
#define TT 12
#define NN 20000
#define FF 9
#define HH 64
#define EE 200000

typedef __hip_bfloat16 bf;
typedef __attribute__((ext_vector_type(8))) short s8v;   // 8 bf16 (4 VGPRs)
typedef __attribute__((ext_vector_type(4))) float f4v;

// ---- big buffers: all-timestep activations (static device globals) -------
__device__ unsigned g_xa[TT*NN*HH];   // 61.4 MB conv1 out, bf16 pair-packed
__device__ unsigned g_ag[TT*NN*HH];   // 61.4 MB aggregation (layer2, then layer3)
__device__ unsigned g_xb[TT*NN*HH];   // 61.4 MB conv2 out
__device__ float2   g_x9[TT*NN*FF];   // 17.3 MB conv3 out (fp32 per batch)
__device__ int      g_rp[NN+1];
__device__ int      g_cnt[NN];
__device__ int      g_csrc[EE];
__device__ float    g_cw[EE];
__device__ float    g_cvec[32];

__device__ __forceinline__ float lo2f(unsigned u){ unsigned v=u<<16; float f; __builtin_memcpy(&f,&v,4); return f; }
__device__ __forceinline__ float hi2f(unsigned u){ unsigned v=u&0xffff0000u; float f; __builtin_memcpy(&f,&v,4); return f; }
__device__ __forceinline__ unsigned short f2us(float f){ bf h=__float2bfloat16(f); unsigned short u; __builtin_memcpy(&u,&h,2); return u; }
__device__ __forceinline__ unsigned pack2(float a0, float a1){ return (unsigned)f2us(a0) | ((unsigned)f2us(a1)<<16); }
__device__ __forceinline__ float elu(float x){ return x>0.f ? x : expm1f(x); }

// ---- CSR build -----------------------------------------------------------
__global__ void k_zero(){
  int i = blockIdx.x*256 + threadIdx.x;
  if(i < NN) g_cnt[i] = 0;
}
__global__ void k_count(const int* __restrict__ dst){
  int e = blockIdx.x*256 + threadIdx.x;
  if(e < EE) atomicAdd(&g_cnt[dst[e]], 1);
}
__global__ void k_scan(){
  __shared__ int part[256];
  const int CH = 79;
  int t = threadIdx.x;
  int base = t*CH;
  int s = 0;
  for(int i=0;i<CH;i++){ int idx=base+i; if(idx<NN) s += g_cnt[idx]; }
  part[t] = s; __syncthreads();
  for(int off=1; off<256; off<<=1){
    int v = (t>=off) ? part[t-off] : 0;
    __syncthreads();
    part[t] += v;
    __syncthreads();
  }
  int run = (t==0) ? 0 : part[t-1];
  for(int i=0;i<CH;i++){
    int idx=base+i;
    if(idx<NN){ run += g_cnt[idx]; g_rp[idx+1] = run; }
  }
  if(t==0) g_rp[0] = 0;
}
__global__ void k_fill(const int* __restrict__ dst, const int* __restrict__ src,
                       const float* __restrict__ ew){
  int e = blockIdx.x*256 + threadIdx.x;
  if(e >= EE) return;
  int d = dst[e];
  int pos = g_rp[d] + atomicAdd(&g_cnt[d], 1);
  g_csrc[pos] = src[e];
  g_cw[pos]   = ew[e];
}

// ---- head precompute -----------------------------------------------------
__global__ void k_head(const float* __restrict__ encW, const float* __restrict__ encb,
                       const float* __restrict__ decW, const float* __restrict__ decb,
                       const float* __restrict__ te){
  __shared__ float c[19];
  int tid = threadIdx.x;
  if(tid < 18){ float s=0.f; for(int j=0;j<64;j++) s += encW[tid*64+j]*decW[j]; c[tid]=s; }
  if(tid == 18){ float s=decb[0]; for(int j=0;j<64;j++) s += encb[j]*decW[j]; c[18]=s; }
  __syncthreads();
  if(tid < FF) g_cvec[tid] = c[tid];
  if(tid < BB){ float s=c[18]; for(int k=0;k<FF;k++) s += te[tid*FF+k]*c[9+k]; g_cvec[FF+tid]=s; }
}

// ---- conv1 (all t): 9 -> 64 shuffle form; t = blockIdx.y -----------------
__global__ void k_conv1_all(const float* __restrict__ g,
                            const float* __restrict__ Wl, const float* __restrict__ bias,
                            const float* __restrict__ Wr){
  int t = blockIdx.y;
  __shared__ float sWl[FF*HH], sWr[FF*HH], sb[HH];
  int tid = threadIdx.x;
  for(int i=tid;i<FF*HH;i+=256){ sWl[i]=Wl[t*FF*HH+i]; sWr[i]=Wr[t*FF*HH+i]; }
  if(tid<HH) sb[tid]=bias[t*HH+tid];
  __syncthreads();
  int lane = tid & 63;
  int half = lane>>5, l9 = lane&31;
  bool act = l9 < FF;
  int wid = (blockIdx.x*256+tid)>>6, nw = gridDim.x*4;
  long gb = ((long)(half*TT+t)*NN)*FF;
  size_t tb = (size_t)t*NN;
  for(int n=wid; n<NN; n+=nw){
    int r0=g_rp[n], r1=g_rp[n+1];
    float dg = fmaxf((float)(r1-r0), 1.f);
    float xv=0.f, agg=0.f;
    if(act) xv = g[gb + (long)n*FF + l9];
    for(int base=r0; base<r1; base+=64){
      int cnt = min(64, r1-base);
      int ms = 0; float mw = 0.f;
      if(lane < cnt){ ms = g_csrc[base+lane]; mw = g_cw[base+lane]; }
      for(int k=0;k<cnt;k+=4){
        int   s0=__shfl(ms,k,64),   s1=__shfl(ms,k+1,64),   s2=__shfl(ms,k+2,64),   s3=__shfl(ms,k+3,64);
        float w0=__shfl(mw,k,64),   w1=__shfl(mw,k+1,64),   w2=__shfl(mw,k+2,64),   w3=__shfl(mw,k+3,64);
        if(act){
          float v0=g[gb+(long)s0*FF+l9], v1=g[gb+(long)s1*FF+l9];
          float v2=g[gb+(long)s2*FF+l9], v3=g[gb+(long)s3*FF+l9];
          agg += w0*v0 + w1*v1 + w2*v2 + w3*v3;
        }
      }
    }
    agg /= dg;
    float a0 = sb[lane], a1 = sb[lane];
    #pragma unroll
    for(int f=0; f<FF; f++){
      float av0=__shfl(agg,f,64),    sv0=__shfl(xv,f,64);
      float av1=__shfl(agg,32+f,64), sv1=__shfl(xv,32+f,64);
      float wl=sWl[f*HH+lane], wr=sWr[f*HH+lane];
      a0 += av0*wl + sv0*wr;
      a1 += av1*wl + sv1*wr;
    }
    g_xa[(tb+n)*HH+lane] = pack2(elu(a0), elu(a1));
  }
}

// ---- agg (all t): gather + reduce; SRC=0 from xa, SRC=1 from xb ---------
template<int SRC>
__global__ void k_agg_all(){
  const unsigned* __restrict__ src = SRC ? g_xb : g_xa;
  int tid = threadIdx.x;
  int lane = tid & 63;
  int grp  = lane >> 4;
  int sub  = lane & 15;
  int wid = (blockIdx.x*256+tid)>>6, nw = gridDim.x*4;
  for(int idx=wid; idx<TT*NN; idx+=nw){
    unsigned ut = (unsigned)idx / NN;
    int n = idx - (int)(ut*NN);
    size_t tb = (size_t)ut*NN;
    int r0=g_rp[n], r1=g_rp[n+1];
    float dg = fmaxf((float)(r1-r0), 1.f);
    float p0[4]={0.f,0.f,0.f,0.f}, p1[4]={0.f,0.f,0.f,0.f};
    for(int base=r0; base<r1; base+=64){
      int cnt = min(64, r1-base);
      int ms = 0; float mw = 0.f;
      if(lane < cnt){ ms = g_csrc[base+lane]; mw = g_cw[base+lane]; }
      for(int k=0;k<cnt;k+=4){
        int   sg = __shfl(ms, k+grp, 64);
        float wg = __shfl(mw, k+grp, 64);
        const uint4 v = *reinterpret_cast<const uint4*>(src + (tb + (size_t)sg)*HH + (sub<<2));
        p0[0]+=wg*lo2f(v.x); p1[0]+=wg*hi2f(v.x);
        p0[1]+=wg*lo2f(v.y); p1[1]+=wg*hi2f(v.y);
        p0[2]+=wg*lo2f(v.z); p1[2]+=wg*hi2f(v.z);
        p0[3]+=wg*lo2f(v.w); p1[3]+=wg*hi2f(v.w);
      }
    }
    #pragma unroll
    for(int q=0;q<4;q++){
      p0[q] += __shfl_xor(p0[q],16,64); p1[q] += __shfl_xor(p1[q],16,64);
      p0[q] += __shfl_xor(p0[q],32,64); p1[q] += __shfl_xor(p1[q],32,64);
    }
    if(lane < 16){
      uint4 o;
      o.x = pack2(p0[0]/dg, p1[0]/dg);
      o.y = pack2(p0[1]/dg, p1[1]/dg);
      o.z = pack2(p0[2]/dg, p1[2]/dg);
      o.w = pack2(p0[3]/dg, p1[3]/dg);
      *reinterpret_cast<uint4*>(g_ag + (tb + (size_t)n)*HH + (lane<<2)) = o;
    }
  }
}

// ---- conv2 GEMM (all t): ELU([AGG|X]@[Wl;Wr]+b), MFMA 16x16x32 bf16 -----
// A: m=lane&15,k=quad*8+j | B: n=lane&15,k=quad*8+j | C/D: col=lane&15,row=quad*4+reg
__global__ __launch_bounds__(256) void k_gemm2_all(const float* __restrict__ Wl,
                                                   const float* __restrict__ bias,
                                                   const float* __restrict__ Wr){
  int t = blockIdx.y;
  __shared__ float sW[128*65];               // row 0..63 = Wl, 64..127 = Wr (pad 65)
  int tid = threadIdx.x;
  for(int i=tid; i<64*64; i+=256){
    int r = i >> 6, c = i & 63;
    sW[r*65+c]      = Wl[(size_t)t*4096 + i];
    sW[(r+64)*65+c] = Wr[(size_t)t*4096 + i];
  }
  __syncthreads();
  int lane = tid & 63, wave = tid >> 6;
  int quad = lane >> 4, col = lane & 15;
  int base16 = blockIdx.x*64 + wave*16;
  if(base16 >= NN) return;
  size_t tb = (size_t)t*NN;
  int nodeA = base16 + col;
  s8v A0[4], A1[4];
  #pragma unroll
  for(int ks=0; ks<4; ks++){
    const unsigned* srcb = (ks < 2) ? g_ag : g_xa;
    int koff = (ks & 1)*32 + quad*8;
    const uint4 u = *reinterpret_cast<const uint4*>(srcb + (tb+nodeA)*HH + koff);
    const uint4 v = *reinterpret_cast<const uint4*>(srcb + (tb+nodeA)*HH + koff + 4);
    unsigned uu[8] = {u.x,u.y,u.z,u.w,v.x,v.y,v.z,v.w};
    #pragma unroll
    for(int j=0;j<8;j++){
      A0[ks][j] = (short)(uu[j] & 0xffffu);
      A1[ks][j] = (short)(uu[j] >> 16);
    }
  }
  #pragma unroll
  for(int nt=0; nt<4; nt++){
    f4v c0 = {0.f,0.f,0.f,0.f}, c1 = {0.f,0.f,0.f,0.f};
    #pragma unroll
    for(int ks=0; ks<4; ks++){
      s8v B;
      #pragma unroll
      for(int j=0;j<8;j++)
        B[j] = (short)f2us(sW[(ks*32+quad*8+j)*65 + nt*16+col]);
      c0 = __builtin_amdgcn_mfma_f32_16x16x32_bf16(A0[ks], B, c0, 0, 0, 0);
      c1 = __builtin_amdgcn_mfma_f32_16x16x32_bf16(A1[ks], B, c1, 0, 0, 0);
    }
    float bn = bias[t*HH + nt*16 + col];
    #pragma unroll
    for(int reg=0; reg<4; reg++){
      int node = base16 + quad*4 + reg;
      g_xb[(tb+node)*HH + nt*16 + col] = pack2(elu(c0[reg]+bn), elu(c1[reg]+bn));
    }
  }
}

// ---- conv3 GEMM (all t): ELU([AGG|X]@[W3l;W3r]+b3) -> g_x9 (fp32x2) -----
__global__ __launch_bounds__(256) void k_gemm3_all(const float* __restrict__ Wl,
                                                   const float* __restrict__ bias,
                                                   const float* __restrict__ Wr){
  int t = blockIdx.y;
  __shared__ float sW[128*10];               // 128 rows x 9 cols (pad 10)
  int tid = threadIdx.x;
  for(int i=tid; i<64*FF; i+=256){
    int r = i/FF, c = i - r*FF;
    sW[r*10+c]      = Wl[(size_t)t*HH*FF + i];
    sW[(r+64)*10+c] = Wr[(size_t)t*HH*FF + i];
  }
  __syncthreads();
  int lane = tid & 63, wave = tid >> 6;
  int quad = lane >> 4, col = lane & 15;
  int base16 = blockIdx.x*64 + wave*16;
  if(base16 >= NN) return;
  size_t tb = (size_t)t*NN;
  int nodeA = base16 + col;
  f4v c0 = {0.f,0.f,0.f,0.f}, c1 = {0.f,0.f,0.f,0.f};
  #pragma unroll
  for(int ks=0; ks<4; ks++){
    const unsigned* srcb = (ks < 2) ? g_ag : g_xb;
    int koff = (ks & 1)*32 + quad*8;
    const uint4 u = *reinterpret_cast<const uint4*>(srcb + (tb+nodeA)*HH + koff);
    const uint4 v = *reinterpret_cast<const uint4*>(srcb + (tb+nodeA)*HH + koff + 4);
    unsigned uu[8] = {u.x,u.y,u.z,u.w,v.x,v.y,v.z,v.w};
    s8v A0, A1, B;
    #pragma unroll
    for(int j=0;j<8;j++){
      A0[j] = (short)(uu[j] & 0xffffu);
      A1[j] = (short)(uu[j] >> 16);
      B[j]  = (col < FF) ? (short)f2us(sW[(ks*32+quad*8+j)*10 + col]) : (short)0;
    }
    c0 = __builtin_amdgcn_mfma_f32_16x16x32_bf16(A0, B, c0, 0, 0, 0);
    c1 = __builtin_amdgcn_mfma_f32_16x16x32_bf16(A1, B, c1, 0, 0, 0);
  }
  if(col < FF){
    float bn = bias[t*FF + col];
    #pragma unroll
    for(int reg=0; reg<4; reg++){
      int node = base16 + quad*4 + reg;
      float2 o; o.x = elu(c0[reg]+bn); o.y = elu(c1[reg]+bn);
      g_x9[(tb+node)*FF + col] = o;
    }
  }
}

// ---- GRU chain (all t in-register) + head + mask ------------------------
__global__ void k_gru_all(const float* __restrict__ g,
                          const float* __restrict__ Wih, const float* __restrict__ Whh,
                          const float* __restrict__ bih, const float* __restrict__ bhh,
                          float* __restrict__ out){
  __shared__ float sWi[TT*FF*27], sWh[TT*FF*27], sbi[TT*27], sbh[TT*27], sc[FF+BB];
  int tid = threadIdx.x;
  for(int i=tid;i<TT*FF*27;i+=256){ sWi[i]=Wih[i]; sWh[i]=Whh[i]; }
  for(int i=tid;i<TT*27;i+=256){ sbi[i]=bih[i]; sbh[i]=bhh[i]; }
  if(tid<FF+BB) sc[tid]=g_cvec[tid];
  __syncthreads();
  int id = blockIdx.x*256 + tid;
  if(id >= BB*NN) return;
  int b = id & 1, n = id >> 1;
  float h[FF];
  #pragma unroll
  for(int f=0;f<FF;f++) h[f] = 0.f;
  for(int t=0;t<TT;t++){
    float x[FF];
    #pragma unroll
    for(int f=0;f<FF;f++){
      float2 p = g_x9[((size_t)t*NN+n)*FF+f];
      x[f] = b ? p.y : p.x;
    }
    float hn[FF];
    #pragma unroll
    for(int f=0;f<FF;f++){
      float gir=sbi[t*27+f], giz=sbi[t*27+9+f], gin=sbi[t*27+18+f];
      float ghr=sbh[t*27+f], ghz=sbh[t*27+9+f], ghn=sbh[t*27+18+f];
      #pragma unroll
      for(int i=0;i<FF;i++){
        gir += x[i]*sWi[t*243+i*27+f];  giz += x[i]*sWi[t*243+i*27+9+f];  gin += x[i]*sWi[t*243+i*27+18+f];
        ghr += h[i]*sWh[t*243+i*27+f];  ghz += h[i]*sWh[t*243+i*27+9+f];  ghn += h[i]*sWh[t*243+i*27+18+f];
      }
      float r = 1.f/(1.f+__expf(-(gir+ghr)));
      float z = 1.f/(1.f+__expf(-(giz+ghz)));
      float nv = tanhf(gin + r*ghn);
      hn[f] = (1.f-z)*nv + z*h[f];
    }
    float acc = sc[FF+b];
    #pragma unroll
    for(int f=0;f<FF;f++){ h[f]=hn[f]; acc += h[f]*sc[f]; }
    size_t gi = (size_t)(b*TT+t)*NN + n;
    float m = (g[gi*FF] != 0.f) ? 1.f : 0.f;
    out[gi] = acc*m;
  }
}

extern "C" void kernel_launch(void* const* d_in, const int* in_sizes, int n_in,
                              void* d_out, int out_size, void* d_ws, size_t ws_size,
                              hipStream_t stream){
  const float* g    = (const float*)d_in[0];
  const float* te   = (const float*)d_in[1];
  const float* ew   = (const float*)d_in[3];
  const int* esrc = (const int*)d_in[4];
  const int* edst = (const int*)d_in[5];
  const float* W1l=(const float*)d_in[6];  const float* b1 =(const float*)d_in[7];  const float* W1r=(const float*)d_in[8];
  const float* W2l=(const float*)d_in[9];  const float* b2 =(const float*)d_in[10]; const float* W2r=(const float*)d_in[11];
  const float* W3l=(const float*)d_in[12]; const float* b3 =(const float*)d_in[13]; const float* W3r=(const float*)d_in[14];
  const float* Wih=(const float*)d_in[15]; const float* Whh=(const float*)d_in[16];
  const float* bih=(const float*)d_in[17]; const float* bhh=(const float*)d_in[18];
  const float* encW=(const float*)d_in[19]; const float* encb=(const float*)d_in[20];
  const float* decW=(const float*)d_in[21]; const float* decb=(const float*)d_in[22];
  float* out = (float*)d_out;

  k_zero <<<(NN+255)/256, 256, 0, stream>>>();
  k_count<<<(EE+255)/256, 256, 0, stream>>>(edst);
  k_scan <<<1, 256, 0, stream>>>();
  k_zero <<<(NN+255)/256, 256, 0, stream>>>();
  k_fill <<<(EE+255)/256, 256, 0, stream>>>(edst, esrc, ew);
  k_head <<<1, 64, 0, stream>>>(encW, encb, decW, decb, te);

  dim3 gcv(512, TT);                 // conv1: 512 blocks x 12 t
  dim3 ggm((NN+63)/64, TT);          // gemm: 313 blocks x 12 t
  k_conv1_all<<<gcv, 256, 0, stream>>>(g, W1l, b1, W1r);
  k_agg_all<0><<<2048, 256, 0, stream>>>();
  k_gemm2_all<<<ggm, 256, 0, stream>>>(W2l, b2, W2r);
  k_agg_all<1><<<2048, 256, 0, stream>>>();
  k_gemm3_all<<<ggm, 256, 0, stream>>>(W3l, b3, W3r);
  k_gru_all<<<(BB*NN+255)/256, 256, 0, stream>>>(g, Wih, Whh, bih, bhh, out);
}

// Round 11
// 808.029 us; speedup vs baseline: 6.2524x; 1.3869x over previous
//
#include <hip/hip_runtime.h>
#include <hip/hip_bf16.h>

#define BB 2
#define TT 12
#define NN 20000
#define FF 9
#define HH 64
#define EE 200000

typedef __hip_bfloat16 bf;
typedef __attribute__((ext_vector_type(8))) short s8v;   // 8 bf16 (4 VGPRs)
typedef __attribute__((ext_vector_type(4))) float f4v;

// ---- big buffers: all-timestep activations (static device globals) -------
__device__ unsigned g_xa[TT*NN*HH];   // 61.4 MB conv1 out, bf16 pair-packed
__device__ unsigned g_ag[TT*NN*HH];   // 61.4 MB aggregation (layer2, then layer3)
__device__ unsigned g_xb[TT*NN*HH];   // 61.4 MB conv2 out
__device__ float2   g_x9[TT*NN*FF];   // 17.3 MB conv3 out (fp32 per batch)
__device__ float    g_gi[TT*27*BB*NN];// 51.8 MB x-projection gi = x@Wih+bih
__device__ int      g_rp[NN+1];
__device__ int      g_cnt[NN];
__device__ int      g_csrc[EE];
__device__ float    g_cw[EE];
__device__ float    g_cvec[32];

__device__ __forceinline__ float lo2f(unsigned u){ unsigned v=u<<16; float f; __builtin_memcpy(&f,&v,4); return f; }
__device__ __forceinline__ float hi2f(unsigned u){ unsigned v=u&0xffff0000u; float f; __builtin_memcpy(&f,&v,4); return f; }
__device__ __forceinline__ unsigned short f2us(float f){ bf h=__float2bfloat16(f); unsigned short u; __builtin_memcpy(&u,&h,2); return u; }
__device__ __forceinline__ unsigned pack2(float a0, float a1){ return (unsigned)f2us(a0) | ((unsigned)f2us(a1)<<16); }
__device__ __forceinline__ float elu(float x){ return x>0.f ? x : expm1f(x); }

// ---- CSR build -----------------------------------------------------------
__global__ void k_zero(){
  int i = blockIdx.x*256 + threadIdx.x;
  if(i < NN) g_cnt[i] = 0;
}
__global__ void k_count(const int* __restrict__ dst){
  int e = blockIdx.x*256 + threadIdx.x;
  if(e < EE) atomicAdd(&g_cnt[dst[e]], 1);
}
__global__ void k_scan(){
  __shared__ int part[256];
  const int CH = 79;
  int t = threadIdx.x;
  int base = t*CH;
  int s = 0;
  for(int i=0;i<CH;i++){ int idx=base+i; if(idx<NN) s += g_cnt[idx]; }
  part[t] = s; __syncthreads();
  for(int off=1; off<256; off<<=1){
    int v = (t>=off) ? part[t-off] : 0;
    __syncthreads();
    part[t] += v;
    __syncthreads();
  }
  int run = (t==0) ? 0 : part[t-1];
  for(int i=0;i<CH;i++){
    int idx=base+i;
    if(idx<NN){ run += g_cnt[idx]; g_rp[idx+1] = run; }
  }
  if(t==0) g_rp[0] = 0;
}
__global__ void k_fill(const int* __restrict__ dst, const int* __restrict__ src,
                       const float* __restrict__ ew){
  int e = blockIdx.x*256 + threadIdx.x;
  if(e >= EE) return;
  int d = dst[e];
  int pos = g_rp[d] + atomicAdd(&g_cnt[d], 1);
  g_csrc[pos] = src[e];
  g_cw[pos]   = ew[e];
}

// ---- head precompute -----------------------------------------------------
__global__ void k_head(const float* __restrict__ encW, const float* __restrict__ encb,
                       const float* __restrict__ decW, const float* __restrict__ decb,
                       const float* __restrict__ te){
  __shared__ float c[19];
  int tid = threadIdx.x;
  if(tid < 18){ float s=0.f; for(int j=0;j<64;j++) s += encW[tid*64+j]*decW[j]; c[tid]=s; }
  if(tid == 18){ float s=decb[0]; for(int j=0;j<64;j++) s += encb[j]*decW[j]; c[18]=s; }
  __syncthreads();
  if(tid < FF) g_cvec[tid] = c[tid];
  if(tid < BB){ float s=c[18]; for(int k=0;k<FF;k++) s += te[tid*FF+k]*c[9+k]; g_cvec[FF+tid]=s; }
}

// ---- conv1 (all t): 9 -> 64 shuffle form; t = blockIdx.y -----------------
__global__ void k_conv1_all(const float* __restrict__ g,
                            const float* __restrict__ Wl, const float* __restrict__ bias,
                            const float* __restrict__ Wr){
  int t = blockIdx.y;
  __shared__ float sWl[FF*HH], sWr[FF*HH], sb[HH];
  int tid = threadIdx.x;
  for(int i=tid;i<FF*HH;i+=256){ sWl[i]=Wl[t*FF*HH+i]; sWr[i]=Wr[t*FF*HH+i]; }
  if(tid<HH) sb[tid]=bias[t*HH+tid];
  __syncthreads();
  int lane = tid & 63;
  int half = lane>>5, l9 = lane&31;
  bool act = l9 < FF;
  int wid = (blockIdx.x*256+tid)>>6, nw = gridDim.x*4;
  long gb = ((long)(half*TT+t)*NN)*FF;
  size_t tb = (size_t)t*NN;
  for(int n=wid; n<NN; n+=nw){
    int r0=g_rp[n], r1=g_rp[n+1];
    float dg = fmaxf((float)(r1-r0), 1.f);
    float xv=0.f, agg=0.f;
    if(act) xv = g[gb + (long)n*FF + l9];
    for(int base=r0; base<r1; base+=64){
      int cnt = min(64, r1-base);
      int ms = 0; float mw = 0.f;
      if(lane < cnt){ ms = g_csrc[base+lane]; mw = g_cw[base+lane]; }
      for(int k=0;k<cnt;k+=4){
        int   s0=__shfl(ms,k,64),   s1=__shfl(ms,k+1,64),   s2=__shfl(ms,k+2,64),   s3=__shfl(ms,k+3,64);
        float w0=__shfl(mw,k,64),   w1=__shfl(mw,k+1,64),   w2=__shfl(mw,k+2,64),   w3=__shfl(mw,k+3,64);
        if(act){
          float v0=g[gb+(long)s0*FF+l9], v1=g[gb+(long)s1*FF+l9];
          float v2=g[gb+(long)s2*FF+l9], v3=g[gb+(long)s3*FF+l9];
          agg += w0*v0 + w1*v1 + w2*v2 + w3*v3;
        }
      }
    }
    agg /= dg;
    float a0 = sb[lane], a1 = sb[lane];
    #pragma unroll
    for(int f=0; f<FF; f++){
      float av0=__shfl(agg,f,64),    sv0=__shfl(xv,f,64);
      float av1=__shfl(agg,32+f,64), sv1=__shfl(xv,32+f,64);
      float wl=sWl[f*HH+lane], wr=sWr[f*HH+lane];
      a0 += av0*wl + sv0*wr;
      a1 += av1*wl + sv1*wr;
    }
    g_xa[(tb+n)*HH+lane] = pack2(elu(a0), elu(a1));
  }
}

// ---- agg (all t): gather + reduce; SRC=0 from xa, SRC=1 from xb ---------
template<int SRC>
__global__ void k_agg_all(){
  const unsigned* __restrict__ src = SRC ? g_xb : g_xa;
  int tid = threadIdx.x;
  int lane = tid & 63;
  int grp  = lane >> 4;
  int sub  = lane & 15;
  int wid = (blockIdx.x*256+tid)>>6, nw = gridDim.x*4;
  for(int idx=wid; idx<TT*NN; idx+=nw){
    unsigned ut = (unsigned)idx / NN;
    int n = idx - (int)(ut*NN);
    size_t tb = (size_t)ut*NN;
    int r0=g_rp[n], r1=g_rp[n+1];
    float dg = fmaxf((float)(r1-r0), 1.f);
    float p0[4]={0.f,0.f,0.f,0.f}, p1[4]={0.f,0.f,0.f,0.f};
    for(int base=r0; base<r1; base+=64){
      int cnt = min(64, r1-base);
      int ms = 0; float mw = 0.f;
      if(lane < cnt){ ms = g_csrc[base+lane]; mw = g_cw[base+lane]; }
      for(int k=0;k<cnt;k+=4){
        int   sg = __shfl(ms, k+grp, 64);
        float wg = __shfl(mw, k+grp, 64);
        const uint4 v = *reinterpret_cast<const uint4*>(src + (tb + (size_t)sg)*HH + (sub<<2));
        p0[0]+=wg*lo2f(v.x); p1[0]+=wg*hi2f(v.x);
        p0[1]+=wg*lo2f(v.y); p1[1]+=wg*hi2f(v.y);
        p0[2]+=wg*lo2f(v.z); p1[2]+=wg*hi2f(v.z);
        p0[3]+=wg*lo2f(v.w); p1[3]+=wg*hi2f(v.w);
      }
    }
    #pragma unroll
    for(int q=0;q<4;q++){
      p0[q] += __shfl_xor(p0[q],16,64); p1[q] += __shfl_xor(p1[q],16,64);
      p0[q] += __shfl_xor(p0[q],32,64); p1[q] += __shfl_xor(p1[q],32,64);
    }
    if(lane < 16){
      uint4 o;
      o.x = pack2(p0[0]/dg, p1[0]/dg);
      o.y = pack2(p0[1]/dg, p1[1]/dg);
      o.z = pack2(p0[2]/dg, p1[2]/dg);
      o.w = pack2(p0[3]/dg, p1[3]/dg);
      *reinterpret_cast<uint4*>(g_ag + (tb + (size_t)n)*HH + (lane<<2)) = o;
    }
  }
}

// ---- conv2 GEMM (all t): ELU([AGG|X]@[Wl;Wr]+b), MFMA 16x16x32 bf16 -----
__global__ __launch_bounds__(256) void k_gemm2_all(const float* __restrict__ Wl,
                                                   const float* __restrict__ bias,
                                                   const float* __restrict__ Wr){
  int t = blockIdx.y;
  __shared__ float sW[128*65];
  int tid = threadIdx.x;
  for(int i=tid; i<64*64; i+=256){
    int r = i >> 6, c = i & 63;
    sW[r*65+c]      = Wl[(size_t)t*4096 + i];
    sW[(r+64)*65+c] = Wr[(size_t)t*4096 + i];
  }
  __syncthreads();
  int lane = tid & 63, wave = tid >> 6;
  int quad = lane >> 4, col = lane & 15;
  int base16 = blockIdx.x*64 + wave*16;
  if(base16 >= NN) return;
  size_t tb = (size_t)t*NN;
  int nodeA = base16 + col;
  s8v A0[4], A1[4];
  #pragma unroll
  for(int ks=0; ks<4; ks++){
    const unsigned* srcb = (ks < 2) ? g_ag : g_xa;
    int koff = (ks & 1)*32 + quad*8;
    const uint4 u = *reinterpret_cast<const uint4*>(srcb + (tb+nodeA)*HH + koff);
    const uint4 v = *reinterpret_cast<const uint4*>(srcb + (tb+nodeA)*HH + koff + 4);
    unsigned uu[8] = {u.x,u.y,u.z,u.w,v.x,v.y,v.z,v.w};
    #pragma unroll
    for(int j=0;j<8;j++){
      A0[ks][j] = (short)(uu[j] & 0xffffu);
      A1[ks][j] = (short)(uu[j] >> 16);
    }
  }
  #pragma unroll
  for(int nt=0; nt<4; nt++){
    f4v c0 = {0.f,0.f,0.f,0.f}, c1 = {0.f,0.f,0.f,0.f};
    #pragma unroll
    for(int ks=0; ks<4; ks++){
      s8v B;
      #pragma unroll
      for(int j=0;j<8;j++)
        B[j] = (short)f2us(sW[(ks*32+quad*8+j)*65 + nt*16+col]);
      c0 = __builtin_amdgcn_mfma_f32_16x16x32_bf16(A0[ks], B, c0, 0, 0, 0);
      c1 = __builtin_amdgcn_mfma_f32_16x16x32_bf16(A1[ks], B, c1, 0, 0, 0);
    }
    float bn = bias[t*HH + nt*16 + col];
    #pragma unroll
    for(int reg=0; reg<4; reg++){
      int node = base16 + quad*4 + reg;
      g_xb[(tb+node)*HH + nt*16 + col] = pack2(elu(c0[reg]+bn), elu(c1[reg]+bn));
    }
  }
}

// ---- conv3 GEMM (all t): ELU([AGG|X]@[W3l;W3r]+b3) -> g_x9 (fp32x2) -----
__global__ __launch_bounds__(256) void k_gemm3_all(const float* __restrict__ Wl,
                                                   const float* __restrict__ bias,
                                                   const float* __restrict__ Wr){
  int t = blockIdx.y;
  __shared__ float sW[128*10];
  int tid = threadIdx.x;
  for(int i=tid; i<64*FF; i+=256){
    int r = i/FF, c = i - r*FF;
    sW[r*10+c]      = Wl[(size_t)t*HH*FF + i];
    sW[(r+64)*10+c] = Wr[(size_t)t*HH*FF + i];
  }
  __syncthreads();
  int lane = tid & 63, wave = tid >> 6;
  int quad = lane >> 4, col = lane & 15;
  int base16 = blockIdx.x*64 + wave*16;
  if(base16 >= NN) return;
  size_t tb = (size_t)t*NN;
  int nodeA = base16 + col;
  f4v c0 = {0.f,0.f,0.f,0.f}, c1 = {0.f,0.f,0.f,0.f};
  #pragma unroll
  for(int ks=0; ks<4; ks++){
    const unsigned* srcb = (ks < 2) ? g_ag : g_xb;
    int koff = (ks & 1)*32 + quad*8;
    const uint4 u = *reinterpret_cast<const uint4*>(srcb + (tb+nodeA)*HH + koff);
    const uint4 v = *reinterpret_cast<const uint4*>(srcb + (tb+nodeA)*HH + koff + 4);
    unsigned uu[8] = {u.x,u.y,u.z,u.w,v.x,v.y,v.z,v.w};
    s8v A0, A1, B;
    #pragma unroll
    for(int j=0;j<8;j++){
      A0[j] = (short)(uu[j] & 0xffffu);
      A1[j] = (short)(uu[j] >> 16);
      B[j]  = (col < FF) ? (short)f2us(sW[(ks*32+quad*8+j)*10 + col]) : (short)0;
    }
    c0 = __builtin_amdgcn_mfma_f32_16x16x32_bf16(A0, B, c0, 0, 0, 0);
    c1 = __builtin_amdgcn_mfma_f32_16x16x32_bf16(A1, B, c1, 0, 0, 0);
  }
  if(col < FF){
    float bn = bias[t*FF + col];
    #pragma unroll
    for(int reg=0; reg<4; reg++){
      int node = base16 + quad*4 + reg;
      float2 o; o.x = elu(c0[reg]+bn); o.y = elu(c1[reg]+bn);
      g_x9[(tb+node)*FF + col] = o;
    }
  }
}

// ---- k_gix: gi = x@Wih + bih for all t (parallel; scalar weights) -------
// GI layout: g_gi[((t*27+j)*BB+b)*NN + n]  (coalesced in n)
__global__ void k_gix(const float* __restrict__ Wih, const float* __restrict__ bih){
  int t = blockIdx.y;
  int n = blockIdx.x*256 + threadIdx.x;
  if(n >= NN) return;
  float x0[FF], x1[FF];
  #pragma unroll
  for(int f=0;f<FF;f++){
    float2 p = g_x9[((size_t)t*NN+n)*FF+f];
    x0[f] = p.x; x1[f] = p.y;
  }
  #pragma unroll
  for(int j=0;j<27;j++){
    float bi = bih[t*27+j];
    float a0 = bi, a1 = bi;
    #pragma unroll
    for(int i=0;i<FF;i++){
      float w = Wih[t*243 + i*27 + j];     // wave-uniform -> s_load
      a0 += x0[i]*w; a1 += x1[i]*w;
    }
    size_t base = ((size_t)(t*27+j)*BB)*NN + n;
    g_gi[base]      = a0;
    g_gi[base + NN] = a1;
  }
}

// ---- k_gru_seq: h-recurrence only; scalar weights, no LDS ---------------
__global__ void k_gru_seq(const float* __restrict__ g, const float* __restrict__ Whh,
                          const float* __restrict__ bhh, float* __restrict__ out){
  int id = blockIdx.x*128 + threadIdx.x;
  if(id >= BB*NN) return;
  int b = id / NN, n = id - b*NN;
  float c9[FF];
  #pragma unroll
  for(int f=0;f<FF;f++) c9[f] = g_cvec[f];
  float cb = g_cvec[FF+b];
  float h[FF];
  #pragma unroll
  for(int f=0;f<FF;f++) h[f] = 0.f;
  for(int t=0;t<TT;t++){
    float gh[27];
    #pragma unroll
    for(int j=0;j<27;j++) gh[j] = bhh[t*27+j];        // s_load
    #pragma unroll
    for(int i=0;i<FF;i++){
      float hi = h[i];
      #pragma unroll
      for(int j=0;j<27;j++) gh[j] += hi * Whh[t*243 + i*27 + j];  // s_load weights
    }
    float gi[27];
    #pragma unroll
    for(int j=0;j<27;j++)
      gi[j] = g_gi[((size_t)(t*27+j)*BB + b)*NN + n]; // coalesced
    float acc = cb;
    #pragma unroll
    for(int f=0;f<FF;f++){
      float r = 1.f/(1.f+__expf(-(gi[f]+gh[f])));
      float z = 1.f/(1.f+__expf(-(gi[9+f]+gh[9+f])));
      float nv = tanhf(gi[18+f] + r*gh[18+f]);
      h[f] = (1.f-z)*nv + z*h[f];
      acc += h[f]*c9[f];
    }
    size_t gidx = (size_t)(b*TT+t)*NN + n;
    float m = (g[gidx*FF] != 0.f) ? 1.f : 0.f;
    out[gidx] = acc*m;
  }
}

extern "C" void kernel_launch(void* const* d_in, const int* in_sizes, int n_in,
                              void* d_out, int out_size, void* d_ws, size_t ws_size,
                              hipStream_t stream){
  const float* g    = (const float*)d_in[0];
  const float* te   = (const float*)d_in[1];
  const float* ew   = (const float*)d_in[3];
  const int* esrc = (const int*)d_in[4];
  const int* edst = (const int*)d_in[5];
  const float* W1l=(const float*)d_in[6];  const float* b1 =(const float*)d_in[7];  const float* W1r=(const float*)d_in[8];
  const float* W2l=(const float*)d_in[9];  const float* b2 =(const float*)d_in[10]; const float* W2r=(const float*)d_in[11];
  const float* W3l=(const float*)d_in[12]; const float* b3 =(const float*)d_in[13]; const float* W3r=(const float*)d_in[14];
  const float* Wih=(const float*)d_in[15]; const float* Whh=(const float*)d_in[16];
  const float* bih=(const float*)d_in[17]; const float* bhh=(const float*)d_in[18];
  const float* encW=(const float*)d_in[19]; const float* encb=(const float*)d_in[20];
  const float* decW=(const float*)d_in[21]; const float* decb=(const float*)d_in[22];
  float* out = (float*)d_out;

  k_zero <<<(NN+255)/256, 256, 0, stream>>>();
  k_count<<<(EE+255)/256, 256, 0, stream>>>(edst);
  k_scan <<<1, 256, 0, stream>>>();
  k_zero <<<(NN+255)/256, 256, 0, stream>>>();
  k_fill <<<(EE+255)/256, 256, 0, stream>>>(edst, esrc, ew);
  k_head <<<1, 64, 0, stream>>>(encW, encb, decW, decb, te);

  dim3 gcv(512, TT);
  dim3 ggm((NN+63)/64, TT);
  dim3 ggi((NN+255)/256, TT);
  k_conv1_all<<<gcv, 256, 0, stream>>>(g, W1l, b1, W1r);
  k_agg_all<0><<<2048, 256, 0, stream>>>();
  k_gemm2_all<<<ggm, 256, 0, stream>>>(W2l, b2, W2r);
  k_agg_all<1><<<2048, 256, 0, stream>>>();
  k_gemm3_all<<<ggm, 256, 0, stream>>>(W3l, b3, W3r);
  k_gix<<<ggi, 256, 0, stream>>>(Wih, bih);
  k_gru_seq<<<(BB*NN+127)/128, 128, 0, stream>>>(g, Whh, bhh, out);
}